// Round 2
// baseline (5824.927 us; speedup 1.0000x reference)
//
#include <hip/hip_runtime.h>
#include <hip/hip_bf16.h>

static constexpr int NB   = 8;       // batches
static constexpr int NN   = 1024;    // nodes
static constexpr int NE   = 32768;   // edges
static constexpr int FIN  = 128;     // T*F input features
static constexpr int FH   = 256;     // hidden
static constexpr int FOUT = 128;     // output features
static constexpr int MR   = NB * NN; // 8192 batch-stacked rows

// ---- graph preprocessing -------------------------------------------------
__global__ void k_deg(const int* __restrict__ dst, int* __restrict__ deg) {
  int e = blockIdx.x * blockDim.x + threadIdx.x;
  if (e < NE) atomicAdd(&deg[dst[e]], 1);
}
__global__ void k_dis(const int* __restrict__ deg, float* __restrict__ dis) {
  int n = blockIdx.x * blockDim.x + threadIdx.x;
  if (n < NN) dis[n] = rsqrtf((float)(deg[n] + 1));  // +1 self loop
}
__global__ void k_adj(const int* __restrict__ src, const int* __restrict__ dst,
                      const float* __restrict__ dis, float* __restrict__ Adj) {
  int t = blockIdx.x * blockDim.x + threadIdx.x;
  if (t < NE) {
    int s = src[t], d = dst[t];
    atomicAdd(&Adj[d * NN + s], dis[s] * dis[d]);
  } else if (t < NE + NN) {
    int n = t - NE;
    atomicAdd(&Adj[n * NN + n], dis[n] * dis[n]);  // self loop
  }
}

// ---- generic 64x64 fp32 tiled GEMM --------------------------------------
// C[M,N] = epilogue( scale * (A@B  [+ A2@B2]) [+ bias] )
// TRANSA: A stored [K,M] row-major (i.e. C uses A^T)
// ATOMIC: blockIdx.z = split-K index, atomicAdd into pre-zeroed C
// else  : blockIdx.z = batch index, offsets A/B/C by sA/sB/sC
template <bool TRANSA, bool DUAL, bool BIAS, bool RELU, bool ATOMIC>
__launch_bounds__(256)
__global__ void gemm64(const float* __restrict__ A, const float* __restrict__ A2,
                       const float* __restrict__ Bm, const float* __restrict__ B2,
                       const float* __restrict__ bias, float* __restrict__ C,
                       int K, int lda, int ldb, int ldc,
                       size_t sA, size_t sB, size_t sC, float scale) {
  static_assert(!(TRANSA && DUAL), "unused combo");
  constexpr int NOP = DUAL ? 2 : 1;
  __shared__ __align__(16) float As[NOP][16][68];
  __shared__ __align__(16) float Bs[NOP][16][68];

  int k0 = 0, k1 = K;
  if constexpr (ATOMIC) {
    int kc = K / gridDim.z;
    k0 = blockIdx.z * kc; k1 = k0 + kc;
  } else {
    size_t z = blockIdx.z;
    A  += z * sA;
    Bm += z * sB;
    C  += z * sC;
    if constexpr (DUAL) { A2 += z * sA; B2 += z * sB; }
  }

  const int tid = threadIdx.x;
  const int tx = tid & 15, ty = tid >> 4;
  const int bm0 = blockIdx.y * 64, bn0 = blockIdx.x * 64;

  float acc[4][4] = {};

  for (int kc0 = k0; kc0 < k1; kc0 += 16) {
    if constexpr (!TRANSA) {
      int arow = tid >> 2, akq = (tid & 3) * 4;
      const float* ap = A + (size_t)(bm0 + arow) * lda + (kc0 + akq);
      #pragma unroll
      for (int j = 0; j < 4; ++j) As[0][akq + j][arow] = ap[j];
      if constexpr (DUAL) {
        const float* ap2 = A2 + (size_t)(bm0 + arow) * lda + (kc0 + akq);
        #pragma unroll
        for (int j = 0; j < 4; ++j) As[1][akq + j][arow] = ap2[j];
      }
    } else {
      int ak = tid >> 4, amq = (tid & 15) * 4;
      const float* ap = A + (size_t)(kc0 + ak) * lda + (bm0 + amq);
      #pragma unroll
      for (int j = 0; j < 4; ++j) As[0][ak][amq + j] = ap[j];
    }
    {
      int bk = tid >> 4, bnq = (tid & 15) * 4;
      const float* bp = Bm + (size_t)(kc0 + bk) * ldb + (bn0 + bnq);
      #pragma unroll
      for (int j = 0; j < 4; ++j) Bs[0][bk][bnq + j] = bp[j];
      if constexpr (DUAL) {
        const float* bp2 = B2 + (size_t)(kc0 + bk) * ldb + (bn0 + bnq);
        #pragma unroll
        for (int j = 0; j < 4; ++j) Bs[1][bk][bnq + j] = bp2[j];
      }
    }
    __syncthreads();
    #pragma unroll
    for (int op = 0; op < NOP; ++op) {
      #pragma unroll
      for (int kk = 0; kk < 16; ++kk) {
        float4 av = *(const float4*)&As[op][kk][ty * 4];
        float4 bv = *(const float4*)&Bs[op][kk][tx * 4];
        float a[4] = {av.x, av.y, av.z, av.w};
        float b[4] = {bv.x, bv.y, bv.z, bv.w};
        #pragma unroll
        for (int i = 0; i < 4; ++i)
          #pragma unroll
          for (int j = 0; j < 4; ++j)
            acc[i][j] = fmaf(a[i], b[j], acc[i][j]);
      }
    }
    __syncthreads();
  }

  #pragma unroll
  for (int i = 0; i < 4; ++i) {
    int row = bm0 + ty * 4 + i;
    #pragma unroll
    for (int j = 0; j < 4; ++j) {
      int col = bn0 + tx * 4 + j;
      float v = acc[i][j] * scale;
      if constexpr (BIAS) v += bias[col];
      if constexpr (RELU) v = fmaxf(v, 0.0f);
      float* cp = C + (size_t)row * ldc + col;
      if constexpr (ATOMIC) atomicAdd(cp, v);
      else *cp = v;
    }
  }
}

// ---- launch --------------------------------------------------------------
extern "C" void kernel_launch(void* const* d_in, const int* in_sizes, int n_in,
                              void* d_out, int out_size, void* d_ws, size_t ws_size,
                              hipStream_t stream) {
  const float* x     = (const float*)d_in[0];   // [8,16,1024,8] == [8192,128] flat
  const int*   ei    = (const int*)d_in[1];
  const float* m_in  = (const float*)d_in[2];   // [32768,1024]
  const float* m_out = (const float*)d_in[3];
  const float* W1    = (const float*)d_in[4];   // [128,256]
  const float* b1    = (const float*)d_in[5];
  const float* Wm    = (const float*)d_in[6];   // [512,256]
  const float* bm    = (const float*)d_in[7];
  const float* W2    = (const float*)d_in[8];   // [256,128]
  const float* b2    = (const float*)d_in[9];
  float* out = (float*)d_out;
  const int* src = ei;
  const int* dst = ei + NE;

  char* w = (char*)d_ws;
  auto alloc = [&](size_t bytes) { char* p = w; w += (bytes + 255) & ~(size_t)255; return p; };
  float* dis = (float*)alloc((size_t)NN * 4);
  int*   deg = (int*)  alloc((size_t)NN * 4);
  float* Adj = (float*)alloc((size_t)NN * NN * 4);     // 4 MB
  float* XW1 = (float*)alloc((size_t)MR * FH * 4);     // 8 MB (reused for XW2)
  float* H   = (float*)alloc((size_t)MR * FH * 4);     // 8 MB
  float* G1  = (float*)alloc((size_t)MR * FH * 4);     // 8 MB
  float* G2  = (float*)alloc((size_t)MR * FH * 4);     // 8 MB
  float* H2  = (float*)alloc((size_t)MR * FH * 4);     // 8 MB
  float* Eb  = (float*)alloc((size_t)NE * FH * 4);     // 32 MB
  float* XW2 = XW1;  // XW1 dead after H is computed
  // total ~76 MB

  hipMemsetAsync(deg, 0, (size_t)NN * 4, stream);
  hipMemsetAsync(Adj, 0, (size_t)NN * NN * 4, stream);
  hipMemsetAsync(H2,  0, (size_t)MR * FH * 4, stream);

  k_deg<<<(NE + 255) / 256, 256, 0, stream>>>(dst, deg);
  k_dis<<<(NN + 255) / 256, 256, 0, stream>>>(deg, dis);
  k_adj<<<(NE + NN + 255) / 256, 256, 0, stream>>>(src, dst, dis, Adj);

  // XW1 = X @ W1   [8192,128]@[128,256] (bias added after aggregation)
  gemm64<false, false, false, false, false>
    <<<dim3(FH / 64, MR / 64, 1), 256, 0, stream>>>(
      x, nullptr, W1, nullptr, nullptr, XW1, FIN, FIN, FH, FH, 0, 0, 0, 1.0f);

  // H_b = relu(Adj @ XW1_b + b1)   (z = batch)
  gemm64<false, false, true, true, false>
    <<<dim3(FH / 64, NN / 64, NB), 256, 0, stream>>>(
      Adj, nullptr, XW1, nullptr, b1, H, NN, NN, FH, FH,
      0, (size_t)NN * FH, (size_t)NN * FH, 1.0f);

  // G1 = H @ Wm[0:256,:] ; G2 = H @ Wm[256:512,:]  (Wm folded through m_in/m_out)
  gemm64<false, false, false, false, false>
    <<<dim3(FH / 64, MR / 64, 1), 256, 0, stream>>>(
      H, nullptr, Wm, nullptr, nullptr, G1, FH, FH, FH, FH, 0, 0, 0, 1.0f);
  gemm64<false, false, false, false, false>
    <<<dim3(FH / 64, MR / 64, 1), 256, 0, stream>>>(
      H, nullptr, Wm + (size_t)FH * FH, nullptr, nullptr, G2, FH, FH, FH, FH, 0, 0, 0, 1.0f);

  for (int b = 0; b < NB; ++b) {
    const float* G1b = G1 + (size_t)b * NN * FH;
    const float* G2b = G2 + (size_t)b * NN * FH;
    // Eb = relu(m_in @ G1b + m_out @ G2b + bm)   [32768,1024]@[1024,256]
    gemm64<false, true, true, true, false>
      <<<dim3(FH / 64, NE / 64, 1), 256, 0, stream>>>(
        m_in, m_out, G1b, G2b, bm, Eb, NN, NN, FH, FH, 0, 0, 0, 1.0f);
    // H2_b += (m_in^T @ Eb) / N    split-K=16, atomic into pre-zeroed H2
    gemm64<true, false, false, false, true>
      <<<dim3(FH / 64, NN / 64, 16), 256, 0, stream>>>(
        m_in, nullptr, Eb, nullptr, nullptr, H2 + (size_t)b * NN * FH,
        NE, NN, FH, FH, 0, 0, 0, 1.0f / NN);
  }

  // XW2 = H2 @ W2   [8192,256]@[256,128]
  gemm64<false, false, false, false, false>
    <<<dim3(FOUT / 64, MR / 64, 1), 256, 0, stream>>>(
      H2, nullptr, W2, nullptr, nullptr, XW2, FH, FH, FOUT, FOUT, 0, 0, 0, 1.0f);

  // out_b = Adj @ XW2_b + b2  (no relu)
  gemm64<false, false, true, false, false>
    <<<dim3(FOUT / 64, NN / 64, NB), 256, 0, stream>>>(
      Adj, nullptr, XW2, nullptr, b2, out, NN, NN, FOUT, FOUT,
      0, (size_t)NN * FOUT, (size_t)NN * FOUT, 1.0f);
}

// Round 3
// 1301.363 us; speedup vs baseline: 4.4760x; 4.4760x over previous
//
#include <hip/hip_runtime.h>
#include <hip/hip_bf16.h>

typedef __attribute__((ext_vector_type(8))) short bf16x8;
typedef __attribute__((ext_vector_type(4))) float f32x4;

static constexpr int NB   = 8;
static constexpr int NN   = 1024;
static constexpr int NE   = 32768;
static constexpr int FIN  = 128;
static constexpr int FH   = 256;
static constexpr int FOUT = 128;
static constexpr int MR   = NB * NN;

__device__ __forceinline__ short f2bf(float f) {
  union { __hip_bfloat16 h; short s; } u;
  u.h = __float2bfloat16(f);
  return u.s;
}

// ---- graph preprocessing -------------------------------------------------
__global__ void k_deg(const int* __restrict__ dst, int* __restrict__ deg) {
  int e = blockIdx.x * blockDim.x + threadIdx.x;
  if (e < NE) atomicAdd(&deg[dst[e]], 1);
}
__global__ void k_dis(const int* __restrict__ deg, float* __restrict__ dis) {
  int n = blockIdx.x * blockDim.x + threadIdx.x;
  if (n < NN) dis[n] = rsqrtf((float)(deg[n] + 1));
}
__global__ void k_adj(const int* __restrict__ src, const int* __restrict__ dst,
                      const float* __restrict__ dis, float* __restrict__ Adj) {
  int t = blockIdx.x * blockDim.x + threadIdx.x;
  if (t < NE) {
    int s = src[t], d = dst[t];
    atomicAdd(&Adj[d * NN + s], dis[s] * dis[d]);
  } else if (t < NE + NN) {
    int n = t - NE;
    atomicAdd(&Adj[n * NN + n], dis[n] * dis[n]);
  }
}

// ---- cast / layout kernels ----------------------------------------------
// Mcat[e][k] bf16: k<1024 -> m_in[e][k], else m_out[e][k-1024]
__global__ __launch_bounds__(256) void k_cat_bf(const float4* __restrict__ mi,
                                                const float4* __restrict__ mo,
                                                short* __restrict__ M) {
  size_t q = (size_t)blockIdx.x * 256 + threadIdx.x;   // quad index over [32768][256]
  size_t e = q >> 8;
  int c = (int)(q & 255) * 4;
  float4 a = mi[q], b = mo[q];
  short4 pa, pb;
  pa.x = f2bf(a.x); pa.y = f2bf(a.y); pa.z = f2bf(a.z); pa.w = f2bf(a.w);
  pb.x = f2bf(b.x); pb.y = f2bf(b.y); pb.z = f2bf(b.z); pb.w = f2bf(b.w);
  *(short4*)&M[e * 2048 + c] = pa;
  *(short4*)&M[e * 2048 + 1024 + c] = pb;
}

// m_inT[n][e] bf16 from m_in[e][n] fp32, 64x64 tiles
__global__ __launch_bounds__(256) void k_transpose_bf(const float* __restrict__ S,
                                                      short* __restrict__ T) {
  __shared__ short tile[64][72];
  int tid = threadIdx.x;
  int e0 = blockIdx.x * 64, n0 = blockIdx.y * 64;
  #pragma unroll
  for (int i = 0; i < 16; ++i) {
    int r = i * 4 + (tid >> 6);
    int c = tid & 63;
    tile[c][r] = f2bf(S[(size_t)(e0 + r) * 1024 + n0 + c]);
  }
  __syncthreads();
  int n = tid >> 2, ec = (tid & 3) * 16;
  #pragma unroll
  for (int q = 0; q < 4; ++q) {
    short4 v;
    v.x = tile[n][ec + q * 4 + 0];
    v.y = tile[n][ec + q * 4 + 1];
    v.z = tile[n][ec + q * 4 + 2];
    v.w = tile[n][ec + q * 4 + 3];
    *(short4*)&T[(size_t)(n0 + n) * 32768 + e0 + ec + q * 4] = v;
  }
}

// WmT[h][f][k] = Wm[h*256+k][f]  (tiny)
__global__ __launch_bounds__(256) void k_wmt(const float* __restrict__ Wm,
                                             short* __restrict__ WmT) {
  int idx = blockIdx.x * 256 + threadIdx.x;   // 2*256*256
  int h = idx >> 16, rem = idx & 65535, f = rem >> 8, k = rem & 255;
  WmT[idx] = f2bf(Wm[(size_t)(h * 256 + k) * 256 + f]);
}

// ---- bf16 MFMA GEMM: C = A[M,K] @ BT[N,K]^T ------------------------------
// 128x128 tile, 4 waves (2x2), 4x4 frags of 16x16x32. LDS stride 40 (pad).
// EPI 0: bf16 TRANSPOSED store Ct[col][row] (+bias[col], relu), z-offset szA/szB/szC
// EPI 1: fp32 atomicAdd C[row][col]*scale, z = split-K chunk of kSplit
// ASRC 1: A from two fp32 buffers (k<1024 -> A1f else A2f), lda=1024 implied
// BSEL 1: B from GT: h=(k>=1024), row stride 8192, col offset bofs+(k&1023)
template <int EPI, int ASRC, int BSEL, bool BIAS, bool RELU>
__launch_bounds__(256)
__global__ void gemm_mfma(const short* __restrict__ Ab, const float* __restrict__ A1f,
                          const float* __restrict__ A2f, const short* __restrict__ BT,
                          const float* __restrict__ bias, void* __restrict__ Cv,
                          int lda, int ldb, int ldc, int K, int kSplit,
                          int bofs, size_t szA, size_t szB, size_t szC, float scale) {
  const int tid = threadIdx.x;
  const int lane = tid & 63, wid = tid >> 6;
  const int wr = wid >> 1, wc = wid & 1;
  const int fr = lane & 15, fq = lane >> 4;
  const int m0 = blockIdx.y * 128, n0 = blockIdx.x * 128;

  __shared__ short As[128 * 40];
  __shared__ short Bs[128 * 40];

  int k0 = 0, k1 = K;
  if constexpr (EPI == 1) {
    k0 = blockIdx.z * kSplit; k1 = k0 + kSplit;
  } else {
    size_t z = blockIdx.z;
    if constexpr (ASRC == 0) Ab += z * szA;
    BT += z * szB;
  }

  const int srow = tid >> 2;          // 0..63 (+64 on pass 1)
  const int scol = (tid & 3) * 8;     // k offset, 8 bf16 = 16 B per lane

  f32x4 acc[4][4] = {};

  for (int kt = k0; kt < k1; kt += 32) {
    bf16x8 av[2], bv[2];
    #pragma unroll
    for (int p = 0; p < 2; ++p) {
      int row = p * 64 + srow;
      if constexpr (ASRC == 0) {
        av[p] = *(const bf16x8*)(Ab + (size_t)(m0 + row) * lda + kt + scol);
      } else {
        const float* ap = ((kt >= 1024) ? A2f : A1f)
                        + (size_t)(m0 + row) * 1024 + (kt & 1023) + scol;
        float4 lo = *(const float4*)ap;
        float4 hi = *(const float4*)(ap + 4);
        bf16x8 v;
        v[0] = f2bf(lo.x); v[1] = f2bf(lo.y); v[2] = f2bf(lo.z); v[3] = f2bf(lo.w);
        v[4] = f2bf(hi.x); v[5] = f2bf(hi.y); v[6] = f2bf(hi.z); v[7] = f2bf(hi.w);
        av[p] = v;
      }
      if constexpr (BSEL == 0) {
        bv[p] = *(const bf16x8*)(BT + (size_t)(n0 + row) * ldb + kt + scol);
      } else {
        size_t h = (kt >= 1024) ? (size_t)(256 * 8192) : 0;
        bv[p] = *(const bf16x8*)(BT + h + (size_t)(n0 + row) * 8192
                                 + bofs + (kt & 1023) + scol);
      }
    }
    __syncthreads();
    #pragma unroll
    for (int p = 0; p < 2; ++p) {
      *(bf16x8*)&As[(p * 64 + srow) * 40 + scol] = av[p];
      *(bf16x8*)&Bs[(p * 64 + srow) * 40 + scol] = bv[p];
    }
    __syncthreads();
    bf16x8 af[4], bfv[4];
    #pragma unroll
    for (int i = 0; i < 4; ++i)
      af[i] = *(const bf16x8*)&As[(wr * 64 + i * 16 + fr) * 40 + fq * 8];
    #pragma unroll
    for (int j = 0; j < 4; ++j)
      bfv[j] = *(const bf16x8*)&Bs[(wc * 64 + j * 16 + fr) * 40 + fq * 8];
    #pragma unroll
    for (int i = 0; i < 4; ++i)
      #pragma unroll
      for (int j = 0; j < 4; ++j)
        acc[i][j] = __builtin_amdgcn_mfma_f32_16x16x32_bf16(af[i], bfv[j], acc[i][j], 0, 0, 0);
  }

  if constexpr (EPI == 0) {
    short* Ct = (short*)Cv + (size_t)blockIdx.z * szC;
    #pragma unroll
    for (int i = 0; i < 4; ++i) {
      int rowb = m0 + wr * 64 + i * 16 + fq * 4;
      #pragma unroll
      for (int j = 0; j < 4; ++j) {
        int col = n0 + wc * 64 + j * 16 + fr;
        float bsv = 0.0f;
        if constexpr (BIAS) bsv = bias[col];
        float v0 = acc[i][j][0] + bsv, v1 = acc[i][j][1] + bsv;
        float v2 = acc[i][j][2] + bsv, v3 = acc[i][j][3] + bsv;
        if constexpr (RELU) {
          v0 = fmaxf(v0, 0.0f); v1 = fmaxf(v1, 0.0f);
          v2 = fmaxf(v2, 0.0f); v3 = fmaxf(v3, 0.0f);
        }
        short4 pk;
        pk.x = f2bf(v0); pk.y = f2bf(v1); pk.z = f2bf(v2); pk.w = f2bf(v3);
        *(short4*)(Ct + (size_t)col * ldc + rowb) = pk;
      }
    }
  } else {
    float* Cf = (float*)Cv;
    #pragma unroll
    for (int i = 0; i < 4; ++i) {
      int rowb = m0 + wr * 64 + i * 16 + fq * 4;
      #pragma unroll
      for (int j = 0; j < 4; ++j) {
        int col = n0 + wc * 64 + j * 16 + fr;
        #pragma unroll
        for (int r = 0; r < 4; ++r)
          atomicAdd(&Cf[(size_t)(rowb + r) * ldc + col], acc[i][j][r] * scale);
      }
    }
  }
}

// ---- fp32 vector GEMM for the small conv/proj steps ----------------------
template <bool BIAS, bool RELU, bool BF16OUT>
__launch_bounds__(256)
__global__ void gemm64(const float* __restrict__ A, const float* __restrict__ Bm,
                       const float* __restrict__ bias, void* __restrict__ Cv,
                       int K, int lda, int ldb, int ldc,
                       size_t sA, size_t sB, size_t sC) {
  __shared__ __align__(16) float As[16][68];
  __shared__ __align__(16) float Bs[16][68];
  size_t z = blockIdx.z;
  A += z * sA; Bm += z * sB;
  const int tid = threadIdx.x;
  const int tx = tid & 15, ty = tid >> 4;
  const int bm0 = blockIdx.y * 64, bn0 = blockIdx.x * 64;
  float acc[4][4] = {};
  for (int kc0 = 0; kc0 < K; kc0 += 16) {
    int arow = tid >> 2, akq = (tid & 3) * 4;
    const float* ap = A + (size_t)(bm0 + arow) * lda + (kc0 + akq);
    #pragma unroll
    for (int j = 0; j < 4; ++j) As[akq + j][arow] = ap[j];
    int bk = tid >> 4, bnq = (tid & 15) * 4;
    const float* bp = Bm + (size_t)(kc0 + bk) * ldb + (bn0 + bnq);
    #pragma unroll
    for (int j = 0; j < 4; ++j) Bs[bk][bnq + j] = bp[j];
    __syncthreads();
    #pragma unroll
    for (int kk = 0; kk < 16; ++kk) {
      float4 avv = *(const float4*)&As[kk][ty * 4];
      float4 bvv = *(const float4*)&Bs[kk][tx * 4];
      float a[4] = {avv.x, avv.y, avv.z, avv.w};
      float b[4] = {bvv.x, bvv.y, bvv.z, bvv.w};
      #pragma unroll
      for (int i = 0; i < 4; ++i)
        #pragma unroll
        for (int j = 0; j < 4; ++j)
          acc[i][j] = fmaf(a[i], b[j], acc[i][j]);
    }
    __syncthreads();
  }
  #pragma unroll
  for (int i = 0; i < 4; ++i) {
    int row = bm0 + ty * 4 + i;
    #pragma unroll
    for (int j = 0; j < 4; ++j) {
      int col = bn0 + tx * 4 + j;
      float v = acc[i][j];
      if constexpr (BIAS) v += bias[col];
      if constexpr (RELU) v = fmaxf(v, 0.0f);
      if constexpr (BF16OUT) ((short*)Cv)[z * sC + (size_t)row * ldc + col] = f2bf(v);
      else                   ((float*)Cv)[z * sC + (size_t)row * ldc + col] = v;
    }
  }
}

// ---- launch --------------------------------------------------------------
extern "C" void kernel_launch(void* const* d_in, const int* in_sizes, int n_in,
                              void* d_out, int out_size, void* d_ws, size_t ws_size,
                              hipStream_t stream) {
  const float* x     = (const float*)d_in[0];
  const int*   ei    = (const int*)d_in[1];
  const float* m_in  = (const float*)d_in[2];
  const float* m_out = (const float*)d_in[3];
  const float* W1    = (const float*)d_in[4];
  const float* b1    = (const float*)d_in[5];
  const float* Wm    = (const float*)d_in[6];
  const float* bm    = (const float*)d_in[7];
  const float* W2    = (const float*)d_in[8];
  const float* b2    = (const float*)d_in[9];
  float* out = (float*)d_out;
  const int* src = ei;
  const int* dst = ei + NE;

  char* w = (char*)d_ws;
  auto alloc = [&](size_t bytes) { char* p = w; w += (bytes + 255) & ~(size_t)255; return p; };
  float* dis  = (float*)alloc((size_t)NN * 4);
  int*   deg  = (int*)  alloc((size_t)NN * 4);
  float* Adj  = (float*)alloc((size_t)NN * NN * 4);       // 4 MB
  float* XW1  = (float*)alloc((size_t)MR * FH * 4);       // 8 MB (reused as XW2)
  short* Hb   = (short*)alloc((size_t)MR * FH * 2);       // 4 MB bf16
  float* H2   = (float*)alloc((size_t)MR * FH * 4);       // 8 MB
  short* GT   = (short*)alloc((size_t)2 * FH * MR * 2);   // 8 MB bf16 [2][256][8192]
  short* WmT  = (short*)alloc((size_t)2 * FH * FH * 2);   // 256 KB
  short* EbT  = (short*)alloc((size_t)FH * NE * 2);       // 16 MB bf16 [256][32768]
  short* m_inT= (short*)alloc((size_t)NN * NE * 2);       // 64 MB bf16 [1024][32768]
  const bool bigws = ws_size >= 252ull * 1024 * 1024;
  short* Mcat = bigws ? (short*)alloc((size_t)NE * 2048 * 2) : nullptr;  // 128 MB
  float* XW2  = XW1;

  hipMemsetAsync(deg, 0, (size_t)NN * 4, stream);
  hipMemsetAsync(Adj, 0, (size_t)NN * NN * 4, stream);
  hipMemsetAsync(H2,  0, (size_t)MR * FH * 4, stream);

  k_deg<<<(NE + 255) / 256, 256, 0, stream>>>(dst, deg);
  k_dis<<<(NN + 255) / 256, 256, 0, stream>>>(deg, dis);
  k_adj<<<(NE + NN + 255) / 256, 256, 0, stream>>>(src, dst, dis, Adj);

  // XW1 = x @ W1   [8192,128]@[128,256] fp32
  gemm64<false, false, false><<<dim3(FH / 64, MR / 64, 1), 256, 0, stream>>>(
      x, W1, nullptr, XW1, FIN, FIN, FH, FH, 0, 0, 0);

  // Hb = relu(Adj @ XW1_b + b1) -> bf16, z = batch
  gemm64<true, true, true><<<dim3(FH / 64, NN / 64, NB), 256, 0, stream>>>(
      Adj, XW1, b1, Hb, NN, NN, FH, FH, 0, (size_t)NN * FH, (size_t)NN * FH);

  // weight transposes + operand casts
  k_wmt<<<512, 256, 0, stream>>>(Wm, WmT);
  if (bigws)
    k_cat_bf<<<NE * 1024 / 4 / 256, 256, 0, stream>>>(
        (const float4*)m_in, (const float4*)m_out, Mcat);
  k_transpose_bf<<<dim3(NE / 64, NN / 64), 256, 0, stream>>>(m_in, m_inT);

  // GT[h] = (Hb @ Wm_h)^T  [256 f][8192 rows], z = h
  gemm_mfma<0, 0, 0, false, false><<<dim3(2, MR / 128, 2), 256, 0, stream>>>(
      Hb, nullptr, nullptr, WmT, nullptr, GT,
      FH, FH, MR, FH, 0, 0, 0, (size_t)FH * FH, (size_t)FH * MR, 1.0f);

  for (int b = 0; b < NB; ++b) {
    // EbT = relu(Mcat @ Gcat_b + bm)^T   [256 f][32768 e]
    if (bigws)
      gemm_mfma<0, 0, 1, true, true><<<dim3(2, NE / 128, 1), 256, 0, stream>>>(
          Mcat, nullptr, nullptr, GT, bm, EbT,
          2048, MR, NE, 2048, 0, b * 1024, 0, 0, 0, 1.0f);
    else
      gemm_mfma<0, 1, 1, true, true><<<dim3(2, NE / 128, 1), 256, 0, stream>>>(
          nullptr, m_in, m_out, GT, bm, EbT,
          1024, MR, NE, 2048, 0, b * 1024, 0, 0, 0, 1.0f);
    // H2_b += (m_inT @ Eb) / N   split-K=16, atomic fp32
    gemm_mfma<1, 0, 0, false, false><<<dim3(2, NN / 128, 16), 256, 0, stream>>>(
        m_inT, nullptr, nullptr, EbT, nullptr, H2 + (size_t)b * NN * FH,
        NE, NE, FH, NE, 2048, 0, 0, 0, 0, 1.0f / NN);
  }

  // XW2 = H2 @ W2   [8192,256]@[256,128] fp32
  gemm64<false, false, false><<<dim3(FOUT / 64, MR / 64, 1), 256, 0, stream>>>(
      H2, W2, nullptr, XW2, FH, FH, FOUT, FOUT, 0, 0, 0);

  // out_b = Adj @ XW2_b + b2
  gemm64<true, false, false><<<dim3(FOUT / 64, NN / 64, NB), 256, 0, stream>>>(
      Adj, XW2, b2, out, NN, NN, FOUT, FOUT, 0, (size_t)NN * FOUT, (size_t)NN * FOUT);
}

// Round 4
// 806.952 us; speedup vs baseline: 7.2184x; 1.6127x over previous
//
#include <hip/hip_runtime.h>
#include <hip/hip_bf16.h>

typedef __attribute__((ext_vector_type(8))) short bf16x8;
typedef __attribute__((ext_vector_type(4))) float f32x4;

static constexpr int NB   = 8;
static constexpr int NN   = 1024;
static constexpr int NE   = 32768;
static constexpr int FIN  = 128;
static constexpr int FH   = 256;
static constexpr int FOUT = 128;
static constexpr int MR   = NB * NN;
static constexpr int HSTR = FH * MR;   // GT h-stride (elements)

__device__ __forceinline__ short f2bf(float f) {
  union { __hip_bfloat16 h; short s; } u;
  u.h = __float2bfloat16(f);
  return u.s;
}

typedef const __attribute__((address_space(1))) void gas_void;
typedef __attribute__((address_space(3))) void las_void;
__device__ __forceinline__ void glds16(short* lds, const short* g) {
  __builtin_amdgcn_global_load_lds((gas_void*)g, (las_void*)lds, 16, 0, 0);
}

// ---- graph preprocessing -------------------------------------------------
__global__ void k_deg(const int* __restrict__ dst, int* __restrict__ deg) {
  int e = blockIdx.x * blockDim.x + threadIdx.x;
  if (e < NE) atomicAdd(&deg[dst[e]], 1);
}
__global__ void k_dis(const int* __restrict__ deg, float* __restrict__ dis) {
  int n = blockIdx.x * blockDim.x + threadIdx.x;
  if (n < NN) dis[n] = rsqrtf((float)(deg[n] + 1));
}
__global__ void k_adj(const int* __restrict__ src, const int* __restrict__ dst,
                      const float* __restrict__ dis, float* __restrict__ Adj) {
  int t = blockIdx.x * blockDim.x + threadIdx.x;
  if (t < NE) {
    int s = src[t], d = dst[t];
    atomicAdd(&Adj[d * NN + s], dis[s] * dis[d]);
  } else if (t < NE + NN) {
    int n = t - NE;
    atomicAdd(&Adj[n * NN + n], dis[n] * dis[n]);
  }
}

// ---- layout / cast kernels ----------------------------------------------
// fp32 [R][C] -> bf16 [C][R]  (tiny weight transposes)
__global__ __launch_bounds__(256) void k_tr(const float* __restrict__ S,
                                            short* __restrict__ D, int R, int C) {
  int idx = blockIdx.x * 256 + threadIdx.x;
  int r = idx / C, c = idx % C;
  D[(size_t)c * R + r] = f2bf(S[idx]);
}
// fp32 -> bf16 streaming cast (float4 -> short4)
__global__ __launch_bounds__(256) void k_cast(const float4* __restrict__ S,
                                              short* __restrict__ D) {
  size_t q = (size_t)blockIdx.x * 256 + threadIdx.x;
  float4 a = S[q];
  short4 p;
  p.x = f2bf(a.x); p.y = f2bf(a.y); p.z = f2bf(a.z); p.w = f2bf(a.w);
  *(short4*)&D[q * 4] = p;
}
// m_in fp32 [32768][1024] -> m_in_bf (row-major bf16) + m_inT (bf16 [1024][32768])
__global__ __launch_bounds__(256) void k_prep_min(const float* __restrict__ S,
                                                  short* __restrict__ Bf,
                                                  short* __restrict__ Tn) {
  __shared__ short tile[64][72];
  int tid = threadIdx.x;
  int e0 = blockIdx.x * 64, n0 = blockIdx.y * 64;
  #pragma unroll
  for (int i = 0; i < 16; ++i) {
    int r = i * 4 + (tid >> 6);
    int c = tid & 63;
    short v = f2bf(S[(size_t)(e0 + r) * 1024 + n0 + c]);
    tile[c][r] = v;
    Bf[(size_t)(e0 + r) * 1024 + n0 + c] = v;
  }
  __syncthreads();
  int n = tid >> 2, ec = (tid & 3) * 16;
  #pragma unroll
  for (int q = 0; q < 4; ++q) {
    short4 v;
    v.x = tile[n][ec + q * 4 + 0];
    v.y = tile[n][ec + q * 4 + 1];
    v.z = tile[n][ec + q * 4 + 2];
    v.w = tile[n][ec + q * 4 + 3];
    *(short4*)&Tn[(size_t)(n0 + n) * 32768 + e0 + ec + q * 4] = v;
  }
}

// ---- bf16 MFMA GEMM core: C = A[M,K] @ BT[N,K]^T -------------------------
// 128x128 tile, BK=64, 4 waves, global_load_lds staging, XOR-swizzled LDS.
// ASRC: 0 = bf16 A (lda), 1 = dual bf16 A (kt<1024 ? Ab : A2b, lda), 2 = fp32 A reg-staged
// BSEL: 0 = BT[N][K] ldb; 1 = GT-style: row stride 8192, col = bofs + z*zcolB + (kt&1023),
//                           + HSTR when kt>=1024
// EPI : 0 = bf16 transposed store Ct[col][row] (short4)   [+bias/relu]
//       1 = fp32 atomicAdd C[row][col]*scale, z = (b, split) with nsplit
//       2 = bf16 store C[row][col]                        [+bias/relu]
//       3 = fp32 store C[row][col] + bias
template <int EPI, int ASRC, int BSEL, bool BIAS, bool RELU>
__launch_bounds__(256)
__global__ void gemm_mfma(const short* __restrict__ Ab, const short* __restrict__ A2b,
                          const float* __restrict__ Af, const short* __restrict__ BT,
                          const float* __restrict__ bias, void* __restrict__ Cv,
                          int lda, int ldb, int ldc, int K, int kSplit, int nsplit,
                          int zcolB, int bofs, size_t szA, size_t szB, size_t szC,
                          float scale) {
  __shared__ __align__(16) short As[128 * 64];
  __shared__ __align__(16) short Bs[128 * 64];

  const int tid = threadIdx.x;
  const int lane = tid & 63, wid = tid >> 6;
  const int wr = wid >> 1, wc = wid & 1;
  const int fr = lane & 15, fq = lane >> 4;
  const int m0 = blockIdx.y * 128, n0 = blockIdx.x * 128;

  int b = blockIdx.z, k0 = 0, k1 = K;
  if constexpr (EPI == 1) {
    b = blockIdx.z / nsplit;
    k0 = (blockIdx.z % nsplit) * kSplit;
    k1 = k0 + kSplit;
  }
  if constexpr (ASRC == 0) Ab += (size_t)b * szA;
  if constexpr (ASRC == 2) Af += (size_t)b * szA;
  BT += (size_t)b * szB;
  const int colB = bofs + b * zcolB;

  // staging constants: lane covers slot (lane&7) of row (base + lane>>3);
  // global k-slot is XOR-swizzled so LDS[row][t] holds global slot t^(row&7)
  const int rq = lane >> 3;
  const int ks = (lane & 7) ^ rq;

  f32x4 acc[4][4] = {};

  for (int kt = k0; kt < k1; kt += 64) {
    // ---- stage A tile [128][64]
    if constexpr (ASRC == 2) {
      #pragma unroll
      for (int p = 0; p < 4; ++p) {
        int i = p * 256 + tid, row = i >> 3, g = i & 7;
        const float* ap = Af + (size_t)(m0 + row) * lda + kt + g * 8;
        bf16x8 v;
        #pragma unroll
        for (int e = 0; e < 8; ++e) v[e] = f2bf(ap[e]);
        *(bf16x8*)&As[row * 64 + ((g ^ (row & 7)) * 8)] = v;
      }
    } else {
      const short* Asrc;
      int kbase;
      if constexpr (ASRC == 1) { Asrc = (kt < 1024) ? Ab : A2b; kbase = kt & 1023; }
      else                     { Asrc = Ab;                     kbase = kt; }
      #pragma unroll
      for (int c = 0; c < 4; ++c) {
        int row = wid * 32 + c * 8 + rq;
        glds16(&As[(wid * 256 + c * 64) * 8],
               Asrc + (size_t)(m0 + row) * lda + kbase + ks * 8);
      }
    }
    // ---- stage B tile [128][64]
    {
      const short* Bsrc;
      int kbase, ldbe;
      if constexpr (BSEL == 1) {
        Bsrc = BT + ((kt >= 1024) ? (size_t)HSTR : 0) + colB;
        kbase = kt & 1023; ldbe = 8192;
      } else {
        Bsrc = BT; kbase = kt; ldbe = ldb;
      }
      #pragma unroll
      for (int c = 0; c < 4; ++c) {
        int row = wid * 32 + c * 8 + rq;
        glds16(&Bs[(wid * 256 + c * 64) * 8],
               Bsrc + (size_t)(n0 + row) * ldbe + kbase + ks * 8);
      }
    }
    __syncthreads();
    // ---- fragments (swizzled read: global slot s at LDS slot s^(fr&7))
    bf16x8 afv[4][2], bfv[4][2];
    #pragma unroll
    for (int i = 0; i < 4; ++i) {
      int row = wr * 64 + i * 16 + fr;
      #pragma unroll
      for (int kh = 0; kh < 2; ++kh)
        afv[i][kh] = *(const bf16x8*)&As[row * 64 + (((kh * 4 + fq) ^ (fr & 7)) * 8)];
    }
    #pragma unroll
    for (int j = 0; j < 4; ++j) {
      int row = wc * 64 + j * 16 + fr;
      #pragma unroll
      for (int kh = 0; kh < 2; ++kh)
        bfv[j][kh] = *(const bf16x8*)&Bs[row * 64 + (((kh * 4 + fq) ^ (fr & 7)) * 8)];
    }
    #pragma unroll
    for (int i = 0; i < 4; ++i)
      #pragma unroll
      for (int j = 0; j < 4; ++j) {
        acc[i][j] = __builtin_amdgcn_mfma_f32_16x16x32_bf16(afv[i][0], bfv[j][0], acc[i][j], 0, 0, 0);
        acc[i][j] = __builtin_amdgcn_mfma_f32_16x16x32_bf16(afv[i][1], bfv[j][1], acc[i][j], 0, 0, 0);
      }
    __syncthreads();
  }

  // ---- epilogue
  #pragma unroll
  for (int i = 0; i < 4; ++i) {
    int rowb = m0 + wr * 64 + i * 16 + fq * 4;
    #pragma unroll
    for (int j = 0; j < 4; ++j) {
      int col = n0 + wc * 64 + j * 16 + fr;
      float bv = 0.0f;
      if constexpr (BIAS) bv = bias[col];
      float v0 = acc[i][j][0] + bv, v1 = acc[i][j][1] + bv;
      float v2 = acc[i][j][2] + bv, v3 = acc[i][j][3] + bv;
      if constexpr (RELU) {
        v0 = fmaxf(v0, 0.0f); v1 = fmaxf(v1, 0.0f);
        v2 = fmaxf(v2, 0.0f); v3 = fmaxf(v3, 0.0f);
      }
      if constexpr (EPI == 0) {
        short* Ct = (short*)Cv + (size_t)b * szC;
        short4 pk;
        pk.x = f2bf(v0); pk.y = f2bf(v1); pk.z = f2bf(v2); pk.w = f2bf(v3);
        *(short4*)(Ct + (size_t)col * ldc + rowb) = pk;
      } else if constexpr (EPI == 1) {
        float* Cf = (float*)Cv + (size_t)b * szC;
        atomicAdd(&Cf[(size_t)(rowb + 0) * ldc + col], acc[i][j][0] * scale);
        atomicAdd(&Cf[(size_t)(rowb + 1) * ldc + col], acc[i][j][1] * scale);
        atomicAdd(&Cf[(size_t)(rowb + 2) * ldc + col], acc[i][j][2] * scale);
        atomicAdd(&Cf[(size_t)(rowb + 3) * ldc + col], acc[i][j][3] * scale);
      } else if constexpr (EPI == 2) {
        short* Cn = (short*)Cv + (size_t)b * szC;
        Cn[(size_t)(rowb + 0) * ldc + col] = f2bf(v0);
        Cn[(size_t)(rowb + 1) * ldc + col] = f2bf(v1);
        Cn[(size_t)(rowb + 2) * ldc + col] = f2bf(v2);
        Cn[(size_t)(rowb + 3) * ldc + col] = f2bf(v3);
      } else {
        float* Cf = (float*)Cv + (size_t)b * szC;
        Cf[(size_t)(rowb + 0) * ldc + col] = v0;
        Cf[(size_t)(rowb + 1) * ldc + col] = v1;
        Cf[(size_t)(rowb + 2) * ldc + col] = v2;
        Cf[(size_t)(rowb + 3) * ldc + col] = v3;
      }
    }
  }
}

// ---- launch --------------------------------------------------------------
extern "C" void kernel_launch(void* const* d_in, const int* in_sizes, int n_in,
                              void* d_out, int out_size, void* d_ws, size_t ws_size,
                              hipStream_t stream) {
  const float* x     = (const float*)d_in[0];
  const int*   ei    = (const int*)d_in[1];
  const float* m_in  = (const float*)d_in[2];
  const float* m_out = (const float*)d_in[3];
  const float* W1    = (const float*)d_in[4];
  const float* b1    = (const float*)d_in[5];
  const float* Wm    = (const float*)d_in[6];
  const float* bm    = (const float*)d_in[7];
  const float* W2    = (const float*)d_in[8];
  const float* b2    = (const float*)d_in[9];
  float* out = (float*)d_out;
  const int* src = ei;
  const int* dst = ei + NE;

  char* w = (char*)d_ws;
  size_t used = 0;
  auto alloc = [&](size_t bytes) {
    char* p = w; size_t r = (bytes + 255) & ~(size_t)255;
    w += r; used += r; return p;
  };
  float* dis   = (float*)alloc((size_t)NN * 4);
  int*   deg   = (int*)  alloc((size_t)NN * 4);
  float* Adj   = (float*)alloc((size_t)NN * NN * 4);      // 4 MB
  short* Adjb  = (short*)alloc((size_t)NN * NN * 2);      // 2 MB
  short* W1T   = (short*)alloc((size_t)FH * FIN * 2);
  short* WmT   = (short*)alloc((size_t)2 * FH * FH * 2);
  short* W2T   = (short*)alloc((size_t)FOUT * FH * 2);
  short* XW1T  = (short*)alloc((size_t)FH * MR * 2);      // 4 MB [256][8192]
  short* Hb    = (short*)alloc((size_t)MR * FH * 2);      // 4 MB [8192][256]
  short* GT    = (short*)alloc((size_t)2 * FH * MR * 2);  // 8 MB [2][256][8192]
  float* H2    = (float*)alloc((size_t)MR * FH * 4);      // 8 MB fp32
  short* XW2T  = (short*)alloc((size_t)FOUT * MR * 2);    // 2 MB [128][8192]
  short* m_in_bf = (short*)alloc((size_t)NE * NN * 2);    // 64 MB
  short* m_out_bf= (short*)alloc((size_t)NE * NN * 2);    // 64 MB
  short* m_inT = (short*)alloc((size_t)NN * NE * 2);      // 64 MB [1024][32768]
  int grp = 1;
  for (int g : {8, 4, 2, 1})
    if (used + (size_t)g * FH * NE * 2 + (1u << 20) <= ws_size) { grp = g; break; }
  short* EbT = (short*)alloc((size_t)grp * FH * NE * 2);  // grp x 16 MB [256][32768]

  hipMemsetAsync(deg, 0, (size_t)NN * 4, stream);
  hipMemsetAsync(Adj, 0, (size_t)NN * NN * 4, stream);
  hipMemsetAsync(H2,  0, (size_t)MR * FH * 4, stream);

  k_deg<<<(NE + 255) / 256, 256, 0, stream>>>(dst, deg);
  k_dis<<<(NN + 255) / 256, 256, 0, stream>>>(deg, dis);
  k_adj<<<(NE + NN + 255) / 256, 256, 0, stream>>>(src, dst, dis, Adj);
  k_cast<<<NN * NN / 4 / 256, 256, 0, stream>>>((const float4*)Adj, Adjb);

  k_tr<<<FIN * FH / 256, 256, 0, stream>>>(W1, W1T, FIN, FH);
  k_tr<<<FH * FH / 256, 256, 0, stream>>>(Wm, WmT, FH, FH);
  k_tr<<<FH * FH / 256, 256, 0, stream>>>(Wm + (size_t)FH * FH, WmT + (size_t)FH * FH, FH, FH);
  k_tr<<<FH * FOUT / 256, 256, 0, stream>>>(W2, W2T, FH, FOUT);
  k_prep_min<<<dim3(NE / 64, NN / 64), 256, 0, stream>>>(m_in, m_in_bf, m_inT);
  k_cast<<<NE * NN / 4 / 256, 256, 0, stream>>>((const float4*)m_out, m_out_bf);

  // XW1T = (x @ W1)^T  bf16 [256][8192]
  gemm_mfma<0, 2, 0, false, false><<<dim3(2, 64, 1), 256, 0, stream>>>(
      nullptr, nullptr, x, W1T, nullptr, XW1T,
      FIN, FIN, MR, FIN, FIN, 1, 0, 0, 0, 0, 0, 1.0f);

  // Hb = relu(Adjb @ XW1_b + b1)  bf16 [8192][256]
  gemm_mfma<2, 0, 1, true, true><<<dim3(2, 8, NB), 256, 0, stream>>>(
      Adjb, nullptr, nullptr, XW1T, b1, Hb,
      NN, 0, FH, NN, NN, 1, 1024, 0, 0, 0, (size_t)NN * FH, 1.0f);

  // GT[h] = WmT[h] @ Hb^T  bf16 [2][256][8192]
  gemm_mfma<2, 0, 0, false, false><<<dim3(64, 2, 2), 256, 0, stream>>>(
      WmT, nullptr, nullptr, Hb, nullptr, GT,
      FH, FH, MR, FH, FH, 1, 0, 0, (size_t)FH * FH, 0, (size_t)FH * MR, 1.0f);

  for (int b0 = 0; b0 < NB; b0 += grp) {
    // EbT[b] = relu([m_in|m_out] @ Gcat_b + bm)^T  bf16 [256][32768]
    gemm_mfma<0, 1, 1, true, true><<<dim3(2, NE / 128, grp), 256, 0, stream>>>(
        m_in_bf, m_out_bf, nullptr, GT, bm, EbT,
        NN, 0, NE, 2 * NN, 2 * NN, 1, 1024, b0 * 1024, 0, 0, (size_t)FH * NE, 1.0f);
    // H2_b += (m_inT @ Eb_b) / N  fp32, split-K=16, atomic
    gemm_mfma<1, 0, 0, false, false><<<dim3(2, 8, grp * 16), 256, 0, stream>>>(
        m_inT, nullptr, nullptr, EbT, nullptr, H2 + (size_t)b0 * NN * FH,
        NE, NE, FH, NE, 2048, 16, 0, 0, 0, (size_t)FH * NE, (size_t)NN * FH, 1.0f / NN);
  }

  // XW2T = (H2 @ W2)^T  bf16 [128][8192]
  gemm_mfma<0, 2, 0, false, false><<<dim3(1, 64, 1), 256, 0, stream>>>(
      nullptr, nullptr, H2, W2T, nullptr, XW2T,
      FH, FH, MR, FH, FH, 1, 0, 0, 0, 0, 0, 1.0f);

  // out_b = Adjb @ XW2_b + b2  fp32 [8192][128]
  gemm_mfma<3, 0, 1, true, false><<<dim3(1, 8, NB), 256, 0, stream>>>(
      Adjb, nullptr, nullptr, XW2T, b2, out,
      NN, 0, FOUT, NN, NN, 1, 1024, 0, 0, 0, (size_t)NN * FOUT, 1.0f);
}

// Round 5
// 740.244 us; speedup vs baseline: 7.8689x; 1.0901x over previous
//
#include <hip/hip_runtime.h>
#include <hip/hip_bf16.h>

typedef __attribute__((ext_vector_type(8))) short bf16x8;
typedef __attribute__((ext_vector_type(4))) float f32x4;

static constexpr int NB   = 8;
static constexpr int NN   = 1024;
static constexpr int NE   = 32768;
static constexpr int FIN  = 128;
static constexpr int FH   = 256;
static constexpr int FOUT = 128;
static constexpr int MR   = NB * NN;

__device__ __forceinline__ short f2bf(float f) {
  union { __hip_bfloat16 h; short s; } u;
  u.h = __float2bfloat16(f);
  return u.s;
}

typedef const __attribute__((address_space(1))) void gas_void;
typedef __attribute__((address_space(3))) void las_void;
__device__ __forceinline__ void glds16(short* lds, const short* g) {
  __builtin_amdgcn_global_load_lds((gas_void*)g, (las_void*)lds, 16, 0, 0);
}
__device__ __forceinline__ void BAR() {
  asm volatile("" ::: "memory");
  __builtin_amdgcn_s_barrier();
  asm volatile("" ::: "memory");
}

// ---- graph preprocessing -------------------------------------------------
__global__ void k_deg(const int* __restrict__ dst, int* __restrict__ deg) {
  int e = blockIdx.x * blockDim.x + threadIdx.x;
  if (e < NE) atomicAdd(&deg[dst[e]], 1);
}
__global__ void k_dis(const int* __restrict__ deg, float* __restrict__ dis) {
  int n = blockIdx.x * blockDim.x + threadIdx.x;
  if (n < NN) dis[n] = rsqrtf((float)(deg[n] + 1));
}
__global__ void k_adj(const int* __restrict__ src, const int* __restrict__ dst,
                      const float* __restrict__ dis, float* __restrict__ Adj) {
  int t = blockIdx.x * blockDim.x + threadIdx.x;
  if (t < NE) {
    int s = src[t], d = dst[t];
    atomicAdd(&Adj[d * NN + s], dis[s] * dis[d]);
  } else if (t < NE + NN) {
    int n = t - NE;
    atomicAdd(&Adj[n * NN + n], dis[n] * dis[n]);
  }
}

// ---- layout / cast kernels ----------------------------------------------
__global__ __launch_bounds__(256) void k_tr(const float* __restrict__ S,
                                            short* __restrict__ D, int R, int C) {
  int idx = blockIdx.x * 256 + threadIdx.x;
  int r = idx / C, c = idx % C;
  D[(size_t)c * R + r] = f2bf(S[idx]);
}
__global__ __launch_bounds__(256) void k_cast(const float4* __restrict__ S,
                                              short* __restrict__ D) {
  size_t q = (size_t)blockIdx.x * 256 + threadIdx.x;
  float4 a = S[q];
  short4 p;
  p.x = f2bf(a.x); p.y = f2bf(a.y); p.z = f2bf(a.z); p.w = f2bf(a.w);
  *(short4*)&D[q * 4] = p;
}
__global__ __launch_bounds__(256) void k_prep_min(const float* __restrict__ S,
                                                  short* __restrict__ Bf,
                                                  short* __restrict__ Tn) {
  __shared__ short tile[64][72];
  int tid = threadIdx.x;
  int e0 = blockIdx.x * 64, n0 = blockIdx.y * 64;
  #pragma unroll
  for (int i = 0; i < 16; ++i) {
    int r = i * 4 + (tid >> 6);
    int c = tid & 63;
    short v = f2bf(S[(size_t)(e0 + r) * 1024 + n0 + c]);
    tile[c][r] = v;
    Bf[(size_t)(e0 + r) * 1024 + n0 + c] = v;
  }
  __syncthreads();
  int n = tid >> 2, ec = (tid & 3) * 16;
  #pragma unroll
  for (int q = 0; q < 4; ++q) {
    short4 v;
    v.x = tile[n][ec + q * 4 + 0];
    v.y = tile[n][ec + q * 4 + 1];
    v.z = tile[n][ec + q * 4 + 2];
    v.w = tile[n][ec + q * 4 + 3];
    *(short4*)&Tn[(size_t)(n0 + n) * 32768 + e0 + ec + q * 4] = v;
  }
}
// H2b[(b*1024+node)][f] = H2all[node][b*256+f]
__global__ __launch_bounds__(256) void k_repack(const float* __restrict__ H2all,
                                                short* __restrict__ H2b) {
  int q = blockIdx.x * 256 + threadIdx.x;      // quad over [8192][64]
  int row = q >> 6, f4 = (q & 63) << 2;
  int b = row >> 10, node = row & 1023;
  float4 v = *(const float4*)&H2all[(size_t)node * 2048 + b * 256 + f4];
  short4 p;
  p.x = f2bf(v.x); p.y = f2bf(v.y); p.z = f2bf(v.z); p.w = f2bf(v.w);
  *(short4*)&H2b[(size_t)row * 256 + f4] = p;
}

// ---- proven 128x128 bf16 MFMA GEMM: C = A[M,K] @ BT[N,K]^T ---------------
// ASRC: 0 = bf16 A; 2 = fp32 A reg-staged
// BSEL: 0 = BT[N][K] ldb; 1 = B rows at ldb 8192 with col offset zB*zcolB
// EPI : 0 = bf16 transposed store Ct[col][row]; 1 = fp32 atomicAdd*scale (z=split)
//       2 = bf16 store C[row][col]; 3 = fp32 store C[row][col]
template <int EPI, int ASRC, int BSEL, bool BIAS, bool RELU>
__launch_bounds__(256)
__global__ void gemm_mfma(const short* __restrict__ Ab, const float* __restrict__ Af,
                          const short* __restrict__ BT, const float* __restrict__ bias,
                          void* __restrict__ Cv,
                          int lda, int ldb, int ldc, int K, int kSplit, int nz2,
                          int zcolB, size_t szA, size_t szB, size_t szC, size_t szC2,
                          float scale) {
  __shared__ __align__(16) short As[128 * 64];
  __shared__ __align__(16) short Bs[128 * 64];

  const int tid = threadIdx.x;
  const int lane = tid & 63, wid = tid >> 6;
  const int wr = wid >> 1, wc = wid & 1;
  const int fr = lane & 15, fq = lane >> 4;
  const int m0 = blockIdx.y * 128, n0 = blockIdx.x * 128;

  int zA = 0, zB = 0, k0 = 0, k1 = K;
  if constexpr (EPI == 1) {
    k0 = blockIdx.z * kSplit; k1 = k0 + kSplit;
  } else {
    zA = (int)blockIdx.z % nz2; zB = (int)blockIdx.z / nz2;
  }
  if constexpr (ASRC == 0) Ab += (size_t)zA * szA;
  else                     Af += (size_t)zA * szA;
  BT += (size_t)zB * szB;
  const int colB = zB * zcolB;

  const int rq = lane >> 3;
  const int ks = (lane & 7) ^ rq;

  f32x4 acc[4][4] = {};

  for (int kt = k0; kt < k1; kt += 64) {
    if constexpr (ASRC == 2) {
      #pragma unroll
      for (int p = 0; p < 4; ++p) {
        int i = p * 256 + tid, row = i >> 3, g = i & 7;
        const float* ap = Af + (size_t)(m0 + row) * lda + kt + g * 8;
        bf16x8 v;
        #pragma unroll
        for (int e = 0; e < 8; ++e) v[e] = f2bf(ap[e]);
        *(bf16x8*)&As[row * 64 + ((g ^ (row & 7)) * 8)] = v;
      }
    } else {
      #pragma unroll
      for (int c = 0; c < 4; ++c) {
        int row = wid * 32 + c * 8 + rq;
        glds16(&As[(wid * 256 + c * 64) * 8],
               Ab + (size_t)(m0 + row) * lda + kt + ks * 8);
      }
    }
    {
      const short* Bsrc;
      int ldbe;
      if constexpr (BSEL == 1) { Bsrc = BT + colB; ldbe = 8192; }
      else                     { Bsrc = BT;        ldbe = ldb;  }
      #pragma unroll
      for (int c = 0; c < 4; ++c) {
        int row = wid * 32 + c * 8 + rq;
        glds16(&Bs[(wid * 256 + c * 64) * 8],
               Bsrc + (size_t)(n0 + row) * ldbe + kt + ks * 8);
      }
    }
    __syncthreads();
    bf16x8 afv[4][2], bfv[4][2];
    #pragma unroll
    for (int i = 0; i < 4; ++i) {
      int row = wr * 64 + i * 16 + fr;
      #pragma unroll
      for (int kh = 0; kh < 2; ++kh)
        afv[i][kh] = *(const bf16x8*)&As[row * 64 + (((kh * 4 + fq) ^ (fr & 7)) * 8)];
    }
    #pragma unroll
    for (int j = 0; j < 4; ++j) {
      int row = wc * 64 + j * 16 + fr;
      #pragma unroll
      for (int kh = 0; kh < 2; ++kh)
        bfv[j][kh] = *(const bf16x8*)&Bs[row * 64 + (((kh * 4 + fq) ^ (fr & 7)) * 8)];
    }
    #pragma unroll
    for (int i = 0; i < 4; ++i)
      #pragma unroll
      for (int j = 0; j < 4; ++j) {
        acc[i][j] = __builtin_amdgcn_mfma_f32_16x16x32_bf16(afv[i][0], bfv[j][0], acc[i][j], 0, 0, 0);
        acc[i][j] = __builtin_amdgcn_mfma_f32_16x16x32_bf16(afv[i][1], bfv[j][1], acc[i][j], 0, 0, 0);
      }
    __syncthreads();
  }

  const size_t cOff = (size_t)zB * szC + (size_t)zA * szC2;
  #pragma unroll
  for (int i = 0; i < 4; ++i) {
    int rowb = m0 + wr * 64 + i * 16 + fq * 4;
    #pragma unroll
    for (int j = 0; j < 4; ++j) {
      int col = n0 + wc * 64 + j * 16 + fr;
      float bv = 0.0f;
      if constexpr (BIAS) bv = bias[col];
      float v0 = acc[i][j][0] + bv, v1 = acc[i][j][1] + bv;
      float v2 = acc[i][j][2] + bv, v3 = acc[i][j][3] + bv;
      if constexpr (RELU) {
        v0 = fmaxf(v0, 0.0f); v1 = fmaxf(v1, 0.0f);
        v2 = fmaxf(v2, 0.0f); v3 = fmaxf(v3, 0.0f);
      }
      if constexpr (EPI == 0) {
        short* Ct = (short*)Cv + cOff;
        short4 pk;
        pk.x = f2bf(v0); pk.y = f2bf(v1); pk.z = f2bf(v2); pk.w = f2bf(v3);
        *(short4*)(Ct + (size_t)col * ldc + rowb) = pk;
      } else if constexpr (EPI == 1) {
        float* Cf = (float*)Cv;
        atomicAdd(&Cf[(size_t)(rowb + 0) * ldc + col], acc[i][j][0] * scale);
        atomicAdd(&Cf[(size_t)(rowb + 1) * ldc + col], acc[i][j][1] * scale);
        atomicAdd(&Cf[(size_t)(rowb + 2) * ldc + col], acc[i][j][2] * scale);
        atomicAdd(&Cf[(size_t)(rowb + 3) * ldc + col], acc[i][j][3] * scale);
      } else if constexpr (EPI == 2) {
        short* Cn = (short*)Cv + cOff;
        Cn[(size_t)(rowb + 0) * ldc + col] = f2bf(v0);
        Cn[(size_t)(rowb + 1) * ldc + col] = f2bf(v1);
        Cn[(size_t)(rowb + 2) * ldc + col] = f2bf(v2);
        Cn[(size_t)(rowb + 3) * ldc + col] = f2bf(v3);
      } else {
        float* Cf = (float*)Cv + cOff;
        Cf[(size_t)(rowb + 0) * ldc + col] = v0;
        Cf[(size_t)(rowb + 1) * ldc + col] = v1;
        Cf[(size_t)(rowb + 2) * ldc + col] = v2;
        Cf[(size_t)(rowb + 3) * ldc + col] = v3;
      }
    }
  }
}

// ---- 8-phase 256x256 edge GEMM: EbT = relu([m_in|m_out] @ G2T^T + bm)^T --
// M=EC edges (chunk), N=2048 (b,f), K=2048 (h,node). Counted-vmcnt pipeline.
__launch_bounds__(512, 2)
__global__ void egemm8(const short* __restrict__ Ain, const short* __restrict__ Aout,
                       const short* __restrict__ G2T, const float* __restrict__ bm,
                       short* __restrict__ EbT, int e0, int EC) {
  __shared__ __align__(16) short As[2][16384];
  __shared__ __align__(16) short Bs[2][16384];

  const int tid = threadIdx.x;
  const int lane = tid & 63, wid = tid >> 6;
  const int wm = wid >> 2, wn = wid & 3;
  const int fr = lane & 15, fq = lane >> 4;
  const int m0 = blockIdx.y * 256;
  const int n0 = blockIdx.x * 256;
  const size_t arow0 = (size_t)(e0 + m0) * 1024;

  const int rl = tid >> 3;                         // 0..63 row-in-issue
  const int ce = ((tid & 7) ^ (rl & 7)) << 3;      // swizzled source col (elements)
  const int ldst = wid << 9;                       // wave-uniform LDS base in issue

  f32x4 acc[8][4] = {};

  auto stageA = [&](int buf, int kt, int iss) {
    const short* s = (kt < 1024 ? Ain : Aout) + arow0
                   + (size_t)(iss * 64 + rl) * 1024 + (kt & 1023) + ce;
    glds16(&As[buf][iss * 4096 + ldst], s);
  };
  auto stageB = [&](int buf, int kt, int iss) {
    const short* s = G2T + (size_t)(n0 + iss * 64 + rl) * 2048 + kt + ce;
    glds16(&Bs[buf][iss * 4096 + ldst], s);
  };

#define EG_PHASE(QM, QN, STAGES, WAITOP)                                          \
  {                                                                               \
    bf16x8 af[4][2], bv[2][2];                                                    \
    _Pragma("unroll")                                                             \
    for (int i = 0; i < 4; ++i) {                                                 \
      int r = wm * 128 + ((QM) * 4 + i) * 16 + fr;                                \
      _Pragma("unroll")                                                           \
      for (int s = 0; s < 2; ++s)                                                 \
        af[i][s] = *(const bf16x8*)&As[buf][r * 64 + (((s * 4 + fq) ^ (r & 7)) << 3)]; \
    }                                                                             \
    _Pragma("unroll")                                                             \
    for (int j = 0; j < 2; ++j) {                                                 \
      int rb = wn * 64 + ((QN) * 2 + j) * 16 + fr;                                \
      _Pragma("unroll")                                                           \
      for (int s = 0; s < 2; ++s)                                                 \
        bv[j][s] = *(const bf16x8*)&Bs[buf][rb * 64 + (((s * 4 + fq) ^ (rb & 7)) << 3)]; \
    }                                                                             \
    STAGES                                                                        \
    WAITOP                                                                        \
    BAR();                                                                        \
    asm volatile("s_waitcnt lgkmcnt(0)" ::: "memory");                            \
    __builtin_amdgcn_s_setprio(1);                                                \
    _Pragma("unroll")                                                             \
    for (int i = 0; i < 4; ++i)                                                   \
      _Pragma("unroll")                                                           \
      for (int j = 0; j < 2; ++j) {                                               \
        acc[(QM) * 4 + i][(QN) * 2 + j] = __builtin_amdgcn_mfma_f32_16x16x32_bf16(\
            af[i][0], bv[j][0], acc[(QM) * 4 + i][(QN) * 2 + j], 0, 0, 0);        \
        acc[(QM) * 4 + i][(QN) * 2 + j] = __builtin_amdgcn_mfma_f32_16x16x32_bf16(\
            af[i][1], bv[j][1], acc[(QM) * 4 + i][(QN) * 2 + j], 0, 0, 0);        \
      }                                                                           \
    __builtin_amdgcn_s_setprio(0);                                                \
    BAR();                                                                        \
  }

  // prologue: stage tile 0 fully
  #pragma unroll
  for (int i = 0; i < 4; ++i) stageA(0, 0, i);
  #pragma unroll
  for (int i = 0; i < 4; ++i) stageB(0, 0, i);
  asm volatile("s_waitcnt vmcnt(0)" ::: "memory");
  BAR();

  constexpr int NT = 2048 / 64;
  for (int t = 0; t < NT; ++t) {
    const int buf = t & 1, nb = buf ^ 1, ktn = (t + 1) * 64;
    const bool pre = (t + 1 < NT);
    EG_PHASE(0, 0, { if (pre) { stageA(nb, ktn, 0); stageA(nb, ktn, 2); } }, ;)
    EG_PHASE(0, 1, { if (pre) { stageB(nb, ktn, 0); stageB(nb, ktn, 1); } },
             asm volatile("s_waitcnt vmcnt(4)" ::: "memory");)
    EG_PHASE(1, 0, { if (pre) { stageB(nb, ktn, 2); stageB(nb, ktn, 3); } }, ;)
    EG_PHASE(1, 1, { if (pre) { stageA(nb, ktn, 1); stageA(nb, ktn, 3); } },
             asm volatile("s_waitcnt vmcnt(2)" ::: "memory");)
  }
#undef EG_PHASE

  // epilogue: transposed bf16 store with bias+relu
  #pragma unroll
  for (int i = 0; i < 8; ++i) {
    int e = m0 + wm * 128 + i * 16 + fq * 4;
    #pragma unroll
    for (int j = 0; j < 4; ++j) {
      int col = n0 + wn * 64 + j * 16 + fr;
      float bb = bm[col & 255];
      float v0 = fmaxf(acc[i][j][0] + bb, 0.0f);
      float v1 = fmaxf(acc[i][j][1] + bb, 0.0f);
      float v2 = fmaxf(acc[i][j][2] + bb, 0.0f);
      float v3 = fmaxf(acc[i][j][3] + bb, 0.0f);
      short4 pk;
      pk.x = f2bf(v0); pk.y = f2bf(v1); pk.z = f2bf(v2); pk.w = f2bf(v3);
      *(short4*)&EbT[(size_t)col * EC + e] = pk;
    }
  }
}

// ---- launch --------------------------------------------------------------
extern "C" void kernel_launch(void* const* d_in, const int* in_sizes, int n_in,
                              void* d_out, int out_size, void* d_ws, size_t ws_size,
                              hipStream_t stream) {
  const float* x     = (const float*)d_in[0];
  const int*   ei    = (const int*)d_in[1];
  const float* m_in  = (const float*)d_in[2];
  const float* m_out = (const float*)d_in[3];
  const float* W1    = (const float*)d_in[4];
  const float* b1    = (const float*)d_in[5];
  const float* Wm    = (const float*)d_in[6];
  const float* bm    = (const float*)d_in[7];
  const float* W2    = (const float*)d_in[8];
  const float* b2    = (const float*)d_in[9];
  float* out = (float*)d_out;
  const int* src = ei;
  const int* dst = ei + NE;

  char* w = (char*)d_ws;
  size_t used = 0;
  auto alloc = [&](size_t bytes) {
    char* p = w; size_t r = (bytes + 255) & ~(size_t)255;
    w += r; used += r; return p;
  };
  float* dis    = (float*)alloc((size_t)NN * 4);
  int*   deg    = (int*)  alloc((size_t)NN * 4);
  short* Adjb   = (short*)alloc((size_t)NN * NN * 2);        // 2 MB (live to end)
  short* W1T    = (short*)alloc((size_t)FH * FIN * 2);
  short* WmT    = (short*)alloc((size_t)2 * FH * FH * 2);
  short* W2T    = (short*)alloc((size_t)FOUT * FH * 2);
  short* G2T    = (short*)alloc((size_t)2048 * 2048 * 2);    // 8 MB [(b,f)][(h,node)]
  float* H2all  = (float*)alloc((size_t)NN * 2048 * 4);      // 8 MB [node][(b,f)]
  short* m_in_bf  = (short*)alloc((size_t)NE * NN * 2);      // 64 MB
  short* m_out_bf = (short*)alloc((size_t)NE * NN * 2);      // 64 MB
  short* m_inT    = (short*)alloc((size_t)NN * NE * 2);      // 64 MB [1024][32768]

  // time-phased union region U: {Adj,XW1T,Hb} -> EbT -> {H2b,XW2T}
  int EC = 4096;
  for (int ec : {32768, 16384, 8192}) {
    size_t need = (size_t)ec * 2048 * 2;
    if (need < (12u << 20)) need = 12u << 20;
    if (used + need + (1u << 20) <= ws_size) { EC = ec; break; }
  }
  size_t ubytes = (size_t)EC * 2048 * 2;
  if (ubytes < (12u << 20)) ubytes = 12u << 20;
  char* U = alloc(ubytes);
  float* Adj  = (float*)U;                  // 4 MB   (early)
  short* XW1T = (short*)(U + (4u << 20));   // 4 MB   (early) [256][8192]
  short* Hb   = (short*)(U + (8u << 20));   // 4 MB   (early) [8192][256]
  short* EbT  = (short*)U;                  // EC*2048*2 (mid) [2048][EC]
  short* H2b  = (short*)U;                  // 4 MB   (late)  [8192][256]
  short* XW2T = (short*)(U + (4u << 20));   // 2 MB   (late)  [128][8192]

  const int nchunk = NE / EC;
  const int nsplit = (EC >= 16384) ? 8 : (EC == 8192 ? 4 : 2);

  hipMemsetAsync(deg, 0, (size_t)NN * 4, stream);
  hipMemsetAsync(Adj, 0, (size_t)NN * NN * 4, stream);
  hipMemsetAsync(H2all, 0, (size_t)NN * 2048 * 4, stream);

  k_deg<<<(NE + 255) / 256, 256, 0, stream>>>(dst, deg);
  k_dis<<<(NN + 255) / 256, 256, 0, stream>>>(deg, dis);
  k_adj<<<(NE + NN + 255) / 256, 256, 0, stream>>>(src, dst, dis, Adj);
  k_cast<<<NN * NN / 4 / 256, 256, 0, stream>>>((const float4*)Adj, Adjb);

  k_tr<<<FIN * FH / 256, 256, 0, stream>>>(W1, W1T, FIN, FH);
  k_tr<<<FH * FH / 256, 256, 0, stream>>>(Wm, WmT, FH, FH);
  k_tr<<<FH * FH / 256, 256, 0, stream>>>(Wm + (size_t)FH * FH, WmT + (size_t)FH * FH, FH, FH);
  k_tr<<<FH * FOUT / 256, 256, 0, stream>>>(W2, W2T, FH, FOUT);
  k_prep_min<<<dim3(NE / 64, NN / 64), 256, 0, stream>>>(m_in, m_in_bf, m_inT);
  k_cast<<<NE * NN / 4 / 256, 256, 0, stream>>>((const float4*)m_out, m_out_bf);

  // XW1T = (x @ W1)^T  bf16 [256][8192]
  gemm_mfma<0, 2, 0, false, false><<<dim3(2, 64, 1), 256, 0, stream>>>(
      nullptr, x, W1T, nullptr, XW1T, FIN, FIN, MR, FIN, 0, 1, 0, 0, 0, 0, 0, 1.0f);

  // Hb = relu(Adjb @ XW1_b + b1)  bf16 [8192][256]
  gemm_mfma<2, 0, 1, true, true><<<dim3(2, 8, NB), 256, 0, stream>>>(
      Adjb, nullptr, XW1T, b1, Hb,
      NN, 0, FH, NN, 0, 1, 1024, 0, 0, (size_t)NN * FH, 0, 1.0f);

  // G2T[(b,f)][(h,node)] = sum_c WmT[h][f][c] * Hb[b][node][c]
  gemm_mfma<2, 0, 0, false, false><<<dim3(8, 2, 16), 256, 0, stream>>>(
      WmT, nullptr, Hb, nullptr, G2T,
      FH, FH, 2048, FH, 0, 2, 0,
      (size_t)FH * FH, (size_t)NN * FH, (size_t)FH * 2048, 1024, 1.0f);

  for (int c = 0; c < nchunk; ++c) {
    // EbT = relu([m_in|m_out] @ G2T^T + bm)^T  bf16 [2048][EC]
    egemm8<<<dim3(8, EC / 256, 1), 512, 0, stream>>>(
        m_in_bf, m_out_bf, G2T, bm, EbT, c * EC, EC);
    // H2all += (m_inT_chunk @ Eb_chunk) / N  fp32 atomics, split-K
    gemm_mfma<1, 0, 0, false, false><<<dim3(16, 8, nsplit), 256, 0, stream>>>(
        m_inT + (size_t)c * EC, nullptr, EbT, nullptr, H2all,
        32768, EC, 2048, EC, EC / nsplit, 1, 0, 0, 0, 0, 0, 1.0f / NN);
  }

  // repack H2all -> H2b bf16 [8192][256]
  k_repack<<<MR * FH / 4 / 256, 256, 0, stream>>>(H2all, H2b);

  // XW2T = (H2b @ W2)^T  bf16 [128][8192]
  gemm_mfma<0, 0, 0, false, false><<<dim3(1, 64, 1), 256, 0, stream>>>(
      H2b, nullptr, W2T, nullptr, XW2T, FH, FH, MR, FH, 0, 1, 0, 0, 0, 0, 0, 1.0f);

  // out_b = Adjb @ XW2_b + b2  fp32 [8192][128]
  gemm_mfma<3, 0, 1, true, false><<<dim3(1, 8, NB), 256, 0, stream>>>(
      Adjb, nullptr, XW2T, b2, out,
      NN, 0, FOUT, NN, 0, 1, 1024, 0, 0, (size_t)NN * FOUT, 0, 1.0f);
}